// Round 5
// baseline (64.239 us; speedup 1.0000x reference)
//
#include <hip/hip_runtime.h>

#define D 8192
#define T_STEPS 100
#define SPIKE_THR 0.5f
#define BLOCK 256
#define COLS_PER_THREAD 4
#define NCHUNK 256
#define ROWS_PER_CHUNK (D / NCHUNK)                    // 32
#define COLBLOCKS (D / (BLOCK * COLS_PER_THREAD))      // 8
#define RED_COLS 64                                    // cols per fused block
#define RED_SEGS (BLOCK / RED_COLS)                    // 4 waves
#define RED_BLOCKS (D / RED_COLS)                      // 128
#define STEPS_PER_SEG (T_STEPS / RED_SEGS)             // 25

typedef float f32x4 __attribute__((ext_vector_type(4)));

// Kernel 1: partial column-dot-products over a 32-row chunk + partial sum(|W|).
// grid = (COLBLOCKS, NCHUNK) = (8, 256) = 2048 blocks, block = 256.
// W is streamed with non-temporal loads (zero reuse).
__global__ void __launch_bounds__(BLOCK)
k_partial(const float* __restrict__ x, const float* __restrict__ W,
          float* __restrict__ ws_drive, float* __restrict__ ws_abs) {
    __shared__ float xs[ROWS_PER_CHUNK];
    __shared__ float red[BLOCK];

    const int chunk = blockIdx.y;
    const int row0  = chunk * ROWS_PER_CHUNK;
    if (threadIdx.x < ROWS_PER_CHUNK)
        xs[threadIdx.x] = x[row0 + threadIdx.x];
    __syncthreads();

    const int j0 = (blockIdx.x * BLOCK + threadIdx.x) * COLS_PER_THREAD;

    float ax = 0.f, ay = 0.f, az = 0.f, aw = 0.f;
    float asum = 0.f;
    #pragma unroll 8
    for (int i = 0; i < ROWS_PER_CHUNK; ++i) {
        const float xv = xs[i];
        const f32x4 w = __builtin_nontemporal_load(
            reinterpret_cast<const f32x4*>(&W[(size_t)(row0 + i) * D + j0]));
        ax = fmaf(xv, w.x, ax);
        ay = fmaf(xv, w.y, ay);
        az = fmaf(xv, w.z, az);
        aw = fmaf(xv, w.w, aw);
        asum += fabsf(w.x) + fabsf(w.y) + fabsf(w.z) + fabsf(w.w);
    }

    float4 acc; acc.x = ax; acc.y = ay; acc.z = az; acc.w = aw;
    *reinterpret_cast<float4*>(&ws_drive[(size_t)chunk * D + j0]) = acc;

    red[threadIdx.x] = asum;
    __syncthreads();
    for (int s = BLOCK / 2; s > 0; s >>= 1) {
        if (threadIdx.x < s) red[threadIdx.x] += red[threadIdx.x + s];
        __syncthreads();
    }
    if (threadIdx.x == 0)
        ws_abs[blockIdx.y * gridDim.x + blockIdx.x] = red[0];
}

// Kernel 2 (fused): reduce ws_drive -> drive for 64 cols, then simulate.
// grid = RED_BLOCKS + 1 = 129, block = 256 = 4 waves.
// Wave `seg` warms up seg*25 steps in registers, then stores its 25
// timesteps (each wave store = 64 consecutive floats = 256 B).
// Block 128 reduces ws_abs -> activity scalar.
// out layout: spikes[T][D], potentials[T][D], activity.
__global__ void __launch_bounds__(BLOCK)
k_fused(const float* __restrict__ ws_drive, const float* __restrict__ ws_abs,
        const float* __restrict__ pot0, float* __restrict__ out) {
    if (blockIdx.x == RED_BLOCKS) {
        __shared__ float red[BLOCK];
        const int n = NCHUNK * COLBLOCKS;  // 2048
        float s = 0.f;
        for (int i = threadIdx.x; i < n; i += BLOCK) s += ws_abs[i];
        red[threadIdx.x] = s;
        __syncthreads();
        for (int st = BLOCK / 2; st > 0; st >>= 1) {
            if (threadIdx.x < st) red[threadIdx.x] += red[threadIdx.x + st];
            __syncthreads();
        }
        if (threadIdx.x == 0)
            out[(size_t)2 * T_STEPS * D] = red[0] / ((float)D * (float)D);
        return;
    }

    __shared__ float part[RED_SEGS][RED_COLS];
    const int col = threadIdx.x & (RED_COLS - 1);
    const int seg = threadIdx.x >> 6;                  // wave id, 0..3
    const int j   = blockIdx.x * RED_COLS + col;

    // each wave sums a 64-chunk segment for its column (256 B/wave loads)
    float s = 0.f;
    const int c0 = seg * (NCHUNK / RED_SEGS);
    #pragma unroll 8
    for (int cc = 0; cc < NCHUNK / RED_SEGS; ++cc)
        s += ws_drive[(size_t)(c0 + cc) * D + j];
    part[seg][col] = s;
    __syncthreads();

    const float d = part[0][col] + part[1][col] + part[2][col] + part[3][col];
    float p = pot0[j];

    // warm up to this wave's time slice (register-only)
    const int t0 = seg * STEPS_PER_SEG;
    for (int t = 0; t < t0; ++t) {
        p += d;
        p = (p >= SPIKE_THR) ? 0.f : p;
    }

    float* __restrict__ spikes = out;
    float* __restrict__ pots   = out + (size_t)T_STEPS * D;

    #pragma unroll
    for (int s2 = 0; s2 < STEPS_PER_SEG; ++s2) {
        const int t = t0 + s2;
        p += d;
        const float sp = (p >= SPIKE_THR) ? 1.f : 0.f;
        p *= (1.f - sp);
        spikes[(size_t)t * D + j] = sp;
        pots[(size_t)t * D + j]   = p;
    }
}

extern "C" void kernel_launch(void* const* d_in, const int* in_sizes, int n_in,
                              void* d_out, int out_size, void* d_ws, size_t ws_size,
                              hipStream_t stream) {
    const float* x   = (const float*)d_in[0];
    const float* W   = (const float*)d_in[1];
    const float* mp0 = (const float*)d_in[2];
    float* out = (float*)d_out;

    float* ws_drive = (float*)d_ws;                       // NCHUNK*D floats = 8 MiB
    float* ws_abs   = ws_drive + (size_t)NCHUNK * D;      // 2048 floats

    dim3 g1(COLBLOCKS, NCHUNK);
    k_partial<<<g1, BLOCK, 0, stream>>>(x, W, ws_drive, ws_abs);
    k_fused<<<RED_BLOCKS + 1, BLOCK, 0, stream>>>(ws_drive, ws_abs, mp0, out);
}

// Round 6
// 55.070 us; speedup vs baseline: 1.1665x; 1.1665x over previous
//
#include <hip/hip_runtime.h>

#define D 8192
#define T_STEPS 100
#define SPIKE_THR 0.5f
#define BLOCK 256
#define COLS_PER_THREAD 4
#define NCHUNK 256
#define ROWS_PER_CHUNK (D / NCHUNK)                    // 32
#define COLBLOCKS (D / (BLOCK * COLS_PER_THREAD))      // 8
#define RED_COLS 64                                    // cols per fused block
#define RED_SEGS (BLOCK / RED_COLS)                    // 4 waves
#define RED_BLOCKS (D / RED_COLS)                      // 128
#define STEPS_PER_SEG (T_STEPS / RED_SEGS)             // 25

// Kernel 1: partial column-dot-products over a 32-row chunk + partial sum(|W|).
// grid = (COLBLOCKS, NCHUNK) = (8, 256) = 2048 blocks, block = 256.
__global__ void __launch_bounds__(BLOCK)
k_partial(const float* __restrict__ x, const float* __restrict__ W,
          float* __restrict__ ws_drive, float* __restrict__ ws_abs) {
    __shared__ float xs[ROWS_PER_CHUNK];
    __shared__ float red[BLOCK];

    const int chunk = blockIdx.y;
    const int row0  = chunk * ROWS_PER_CHUNK;
    if (threadIdx.x < ROWS_PER_CHUNK)
        xs[threadIdx.x] = x[row0 + threadIdx.x];
    __syncthreads();

    const int j0 = (blockIdx.x * BLOCK + threadIdx.x) * COLS_PER_THREAD;

    float ax = 0.f, ay = 0.f, az = 0.f, aw = 0.f;
    float asum = 0.f;
    #pragma unroll 8
    for (int i = 0; i < ROWS_PER_CHUNK; ++i) {
        const float xv = xs[i];
        const float4 w = *reinterpret_cast<const float4*>(
            &W[(size_t)(row0 + i) * D + j0]);
        ax = fmaf(xv, w.x, ax);
        ay = fmaf(xv, w.y, ay);
        az = fmaf(xv, w.z, az);
        aw = fmaf(xv, w.w, aw);
        asum += fabsf(w.x) + fabsf(w.y) + fabsf(w.z) + fabsf(w.w);
    }

    float4 acc; acc.x = ax; acc.y = ay; acc.z = az; acc.w = aw;
    *reinterpret_cast<float4*>(&ws_drive[(size_t)chunk * D + j0]) = acc;

    red[threadIdx.x] = asum;
    __syncthreads();
    for (int s = BLOCK / 2; s > 0; s >>= 1) {
        if (threadIdx.x < s) red[threadIdx.x] += red[threadIdx.x + s];
        __syncthreads();
    }
    if (threadIdx.x == 0)
        ws_abs[blockIdx.y * gridDim.x + blockIdx.x] = red[0];
}

// Kernel 2 (fused): reduce ws_drive -> drive for 64 cols, then simulate.
// grid = RED_BLOCKS + 1 = 129, block = 256 = 4 waves.
// Wave `seg` warms up seg*25 steps in registers, then stores its 25
// timesteps (each wave store = 64 consecutive floats = 256 B).
// Block 128 reduces ws_abs -> activity scalar.
// out layout: spikes[T][D], potentials[T][D], activity.
__global__ void __launch_bounds__(BLOCK)
k_fused(const float* __restrict__ ws_drive, const float* __restrict__ ws_abs,
        const float* __restrict__ pot0, float* __restrict__ out) {
    if (blockIdx.x == RED_BLOCKS) {
        __shared__ float red[BLOCK];
        const int n = NCHUNK * COLBLOCKS;  // 2048
        float s = 0.f;
        for (int i = threadIdx.x; i < n; i += BLOCK) s += ws_abs[i];
        red[threadIdx.x] = s;
        __syncthreads();
        for (int st = BLOCK / 2; st > 0; st >>= 1) {
            if (threadIdx.x < st) red[threadIdx.x] += red[threadIdx.x + st];
            __syncthreads();
        }
        if (threadIdx.x == 0)
            out[(size_t)2 * T_STEPS * D] = red[0] / ((float)D * (float)D);
        return;
    }

    __shared__ float part[RED_SEGS][RED_COLS];
    const int col = threadIdx.x & (RED_COLS - 1);
    const int seg = threadIdx.x >> 6;                  // wave id, 0..3
    const int j   = blockIdx.x * RED_COLS + col;

    // each wave sums a 64-chunk segment for its column (256 B/wave loads)
    float s = 0.f;
    const int c0 = seg * (NCHUNK / RED_SEGS);
    #pragma unroll 8
    for (int cc = 0; cc < NCHUNK / RED_SEGS; ++cc)
        s += ws_drive[(size_t)(c0 + cc) * D + j];
    part[seg][col] = s;
    __syncthreads();

    const float d = part[0][col] + part[1][col] + part[2][col] + part[3][col];
    float p = pot0[j];

    // warm up to this wave's time slice (register-only)
    const int t0 = seg * STEPS_PER_SEG;
    for (int t = 0; t < t0; ++t) {
        p += d;
        p = (p >= SPIKE_THR) ? 0.f : p;
    }

    float* __restrict__ spikes = out;
    float* __restrict__ pots   = out + (size_t)T_STEPS * D;

    #pragma unroll
    for (int s2 = 0; s2 < STEPS_PER_SEG; ++s2) {
        const int t = t0 + s2;
        p += d;
        const float sp = (p >= SPIKE_THR) ? 1.f : 0.f;
        p *= (1.f - sp);
        spikes[(size_t)t * D + j] = sp;
        pots[(size_t)t * D + j]   = p;
    }
}

extern "C" void kernel_launch(void* const* d_in, const int* in_sizes, int n_in,
                              void* d_out, int out_size, void* d_ws, size_t ws_size,
                              hipStream_t stream) {
    const float* x   = (const float*)d_in[0];
    const float* W   = (const float*)d_in[1];
    const float* mp0 = (const float*)d_in[2];
    float* out = (float*)d_out;

    float* ws_drive = (float*)d_ws;                       // NCHUNK*D floats = 8 MiB
    float* ws_abs   = ws_drive + (size_t)NCHUNK * D;      // 2048 floats

    dim3 g1(COLBLOCKS, NCHUNK);
    k_partial<<<g1, BLOCK, 0, stream>>>(x, W, ws_drive, ws_abs);
    k_fused<<<RED_BLOCKS + 1, BLOCK, 0, stream>>>(ws_drive, ws_abs, mp0, out);
}